// Round 1
// baseline (330.807 us; speedup 1.0000x reference)
//
#include <hip/hip_runtime.h>

// Correlation (FlowNet-style), kernel=1, stride=1, md=pad=4.
// B=8, C=128, H=W=192 -> out [8, 81, 192, 192] fp32.
//
// Decomposition:
//  - block = 576 threads = 9 waves; wave w handles displacement row dy = w.
//  - lane: tx = lane&7 (covers 4 x-pixels), ty = lane>>3 (y row). Tile 8x32.
//  - accumulators: acc[9 dx][4 px] = 36 VGPRs.
//  - channels staged through LDS in chunks of CB=8, register-prefetched.
//  - LDS row stride 40 floats: x1 tile [CB][8][40], x2 tile [CB][16][40]
//    (x2 rows y0-4 .. y0+11, cols x0-4 .. x0+35, zero-filled out of range).

#define NT 576

__global__ __launch_bounds__(NT)
void corr_kernel(const float* __restrict__ x1g, const float* __restrict__ x2g,
                 float* __restrict__ outg) {
  constexpr int Cc = 128, Hh = 192, Ww = 192;
  constexpr int THt = 8, TWt = 32, XTs = 40, CBc = 8;
  constexpr int X2OFF  = CBc * THt * XTs;        // 2560 floats (x1 region size)
  constexpr int NX1F4  = CBc * THt * (TWt / 4);  // 512 float4 slots for x1
  constexpr int NX2F4  = CBc * 16 * (XTs / 4);   // 1280 float4 slots for x2
  constexpr int CSTRIDE = CBc * Hh * Ww;         // float advance per chunk

  __shared__ __align__(16) float lds[X2OFF + CBc * 16 * XTs];  // 30.7 KB

  // XCD-chunked swizzle: 1152 blocks = 8 XCDs x 144 tiles, yt fastest so
  // y-adjacent tiles (sharing x2 halo rows) stay on one XCD's L2.
  const int bid  = blockIdx.x;
  const int tile = (bid & 7) * 144 + (bid >> 3);
  const int yt = tile % 24;
  const int t2 = tile / 24;
  const int xt = t2 % 6;
  const int b  = t2 / 6;
  const int y0 = yt * THt, x0 = xt * TWt;

  const int tid  = (int)threadIdx.x;
  const int w    = tid >> 6;        // wave index = dy (0..8)
  const int lane = tid & 63;
  const int tx   = lane & 7;
  const int ty   = lane >> 3;

  // ---- precompute staging slots (4 float4 slots per thread) ----
  // slot 0: x1, slots 1..3: x2. has[] = slot exists (must store, maybe zero),
  // inb[] = global address in-bounds (do the load).
  const float* gp[4];
  int  ldso[4];
  bool has[4], inb[4];
  {
    has[0] = (tid < NX1F4);
    inb[0] = has[0];
    const int cc = tid >> 6, r = (tid >> 3) & 7, f = tid & 7;
    ldso[0] = (cc * THt + r) * XTs + 4 * f;
    gp[0] = x1g + (((size_t)(b * Cc + cc) * Hh + (y0 + r)) * Ww + x0 + 4 * f);
#pragma unroll
    for (int k = 0; k < 3; ++k) {
      const int i = tid + k * NT;
      const bool h = (i < NX2F4);
      const int cc2 = i / 160;
      const int rem = i - cc2 * 160;
      const int r2  = rem / 10;
      const int f2  = rem - r2 * 10;
      const int gy = y0 + r2 - 4;
      const int gx = x0 + 4 * f2 - 4;
      // W=192 and tile offsets are multiples of 4 -> each float4 is fully
      // in-range or fully out-of-range; same for rows.
      has[1 + k] = h;
      inb[1 + k] = h && (gy >= 0) && (gy < Hh) && (gx >= 0) && (gx < Ww);
      ldso[1 + k] = X2OFF + (cc2 * 16 + r2) * XTs + 4 * f2;
      gp[1 + k] = x2g + (((size_t)(b * Cc + cc2) * Hh + gy) * Ww + gx);
    }
  }

  float4 p[4];
  auto issue = [&]() {
#pragma unroll
    for (int s = 0; s < 4; ++s) {
      float4 v = make_float4(0.f, 0.f, 0.f, 0.f);
      if (inb[s]) v = *(const float4*)(gp[s]);
      p[s] = v;
      gp[s] += CSTRIDE;
    }
  };

  float acc[9][4];
#pragma unroll
  for (int d = 0; d < 9; ++d)
#pragma unroll
    for (int q = 0; q < 4; ++q) acc[d][q] = 0.f;

  issue();  // prefetch chunk 0

  const int o1 = ty * XTs + 4 * tx;                 // x1 read offset
  const int o2 = X2OFF + (ty + w) * XTs + 4 * tx;   // x2 read offset (row ty+dy)

#pragma unroll 1
  for (int ck = 0; ck < Cc / CBc; ++ck) {
    __syncthreads();  // previous chunk's compute done; LDS free
#pragma unroll
    for (int s = 0; s < 4; ++s)
      if (has[s]) *(float4*)&lds[ldso[s]] = p[s];
    __syncthreads();
    if (ck != Cc / CBc - 1) issue();  // overlap next chunk's HBM latency

#pragma unroll
    for (int cc = 0; cc < CBc; ++cc) {
      const float4 a  = *(const float4*)&lds[cc * (THt * XTs) + o1];
      const float* rr = &lds[cc * (16 * XTs) + o2];
      const float4 b0 = *(const float4*)(rr + 0);
      const float4 b1 = *(const float4*)(rr + 4);
      const float4 b2 = *(const float4*)(rr + 8);
      const float rv[12] = {b0.x, b0.y, b0.z, b0.w,
                            b1.x, b1.y, b1.z, b1.w,
                            b2.x, b2.y, b2.z, b2.w};
      const float av[4] = {a.x, a.y, a.z, a.w};
#pragma unroll
      for (int dx = 0; dx < 9; ++dx) {
        acc[dx][0] += av[0] * rv[dx + 0];
        acc[dx][1] += av[1] * rv[dx + 1];
        acc[dx][2] += av[2] * rv[dx + 2];
        acc[dx][3] += av[3] * rv[dx + 3];
      }
    }
  }

  // ---- epilogue: out[b][w*9+dx][y0+ty][x0+4tx .. +3] ----
  const float invc = 1.0f / 128.0f;
  const int ybase = y0 + ty, xbase = x0 + 4 * tx;
#pragma unroll
  for (int dx = 0; dx < 9; ++dx) {
    float4 o;
    o.x = acc[dx][0] * invc;
    o.y = acc[dx][1] * invc;
    o.z = acc[dx][2] * invc;
    o.w = acc[dx][3] * invc;
    const size_t oidx =
        (((size_t)b * 81 + (w * 9 + dx)) * Hh + ybase) * Ww + xbase;
    *(float4*)&outg[oidx] = o;
  }
}

extern "C" void kernel_launch(void* const* d_in, const int* in_sizes, int n_in,
                              void* d_out, int out_size, void* d_ws, size_t ws_size,
                              hipStream_t stream) {
  const float* x1 = (const float*)d_in[0];
  const float* x2 = (const float*)d_in[1];
  float* out = (float*)d_out;
  // grid: 8 batches x 6 x-tiles x 24 y-tiles = 1152 blocks (divisible by 8 XCDs)
  corr_kernel<<<dim3(1152), dim3(NT), 0, stream>>>(x1, x2, out);
}

// Round 2
// 297.317 us; speedup vs baseline: 1.1126x; 1.1126x over previous
//
#include <hip/hip_runtime.h>

// Correlation (FlowNet-style), kernel=1, stride=1, md=pad=4.
// B=8, C=128, H=W=192 -> out [8, 81, 192, 192] fp32.
//
// Round-2 design: NO LDS, no barriers.
//  - 1152 tiles (8 b x 6 xt x 24 yt), tile = 8 rows x 32 cols.
//  - block = 192 threads = 3 waves; each wave owns one dy; 3 blocks per tile
//    cover the 9 dy values. Grid = 3456 blocks.
//  - lane: tx = lane&7 -> 4 consecutive x pixels; ty = lane>>3 -> row.
//  - per channel: 1 x1 float4 + 3 x2 float4 loaded straight from global
//    (served by L1/L2; the 9 dy-waves of a tile are adjacent blocks on the
//    same XCD via the swizzle, so x1/x2 re-reads hit that XCD's L2).
//  - acc[9 dx][4 px] registers; epilogue writes 9 float4.

#define BLOCK 192

__global__ __launch_bounds__(BLOCK)
void corr_kernel(const float* __restrict__ x1g, const float* __restrict__ x2g,
                 float* __restrict__ outg) {
  constexpr int Cc = 128, Hh = 192, Ww = 192;
  constexpr int HW = Hh * Ww;  // 36864

  // XCD-chunked swizzle: 3456 blocks = 8 XCDs x 432. Consecutive wid on one
  // XCD => the 3 blocks (9 dy) of a tile + yt-adjacent tiles share L2.
  const int bid = blockIdx.x;
  const int wid = (bid & 7) * 432 + (bid >> 3);
  const int tile = wid / 3;          // 0..1151
  const int g    = wid - 3 * tile;   // 0..2
  const int yt = tile % 24;
  const int t2 = tile / 24;
  const int xt = t2 % 6;
  const int b  = t2 / 6;

  const int w    = (int)threadIdx.x >> 6;  // 0..2
  const int lane = (int)threadIdx.x & 63;
  const int tx   = lane & 7;
  const int ty   = lane >> 3;
  const int dy   = g * 3 + w;              // 0..8

  const int y  = yt * 8 + ty;
  const int xb = xt * 32 + 4 * tx;
  const int row = y + dy - 4;
  const bool rowok = (row >= 0) && (row < Hh);
  const int rowc = rowok ? row : 0;

  // float4 windows are 4-aligned -> each slot is fully in- or out-of-range.
  const bool ok0 = rowok && (xb >= 4);          // cols xb-4 .. xb-1
  const bool ok1 = rowok;                       // cols xb   .. xb+3
  const bool ok2 = rowok && (xb <= 184);        // cols xb+4 .. xb+7

  const float* p1 = x1g + ((size_t)(b * Cc) * Hh + y) * Ww + xb;
  const float* p2 = x2g + ((size_t)(b * Cc) * Hh + rowc) * Ww + (xb - 4);

  float acc[9][4];
#pragma unroll
  for (int d = 0; d < 9; ++d)
#pragma unroll
    for (int q = 0; q < 4; ++q) acc[d][q] = 0.f;

#pragma unroll 2
  for (int c = 0; c < Cc; ++c) {
    const float4 a = *(const float4*)p1;
    float4 b0 = make_float4(0.f, 0.f, 0.f, 0.f);
    float4 b1 = b0, b2 = b0;
    if (ok0) b0 = *(const float4*)(p2);
    if (ok1) b1 = *(const float4*)(p2 + 4);
    if (ok2) b2 = *(const float4*)(p2 + 8);
    p1 += HW;
    p2 += HW;

    const float rv[12] = {b0.x, b0.y, b0.z, b0.w,
                          b1.x, b1.y, b1.z, b1.w,
                          b2.x, b2.y, b2.z, b2.w};
    const float av[4] = {a.x, a.y, a.z, a.w};
#pragma unroll
    for (int dx = 0; dx < 9; ++dx) {
      acc[dx][0] += av[0] * rv[dx + 0];
      acc[dx][1] += av[1] * rv[dx + 1];
      acc[dx][2] += av[2] * rv[dx + 2];
      acc[dx][3] += av[3] * rv[dx + 3];
    }
  }

  // epilogue: out[b][dy*9+dx][y][xb..xb+3]
  const float invc = 1.0f / 128.0f;
#pragma unroll
  for (int dx = 0; dx < 9; ++dx) {
    float4 o;
    o.x = acc[dx][0] * invc;
    o.y = acc[dx][1] * invc;
    o.z = acc[dx][2] * invc;
    o.w = acc[dx][3] * invc;
    const size_t oidx =
        (((size_t)b * 81 + (dy * 9 + dx)) * Hh + y) * Ww + xb;
    *(float4*)&outg[oidx] = o;
  }
}

extern "C" void kernel_launch(void* const* d_in, const int* in_sizes, int n_in,
                              void* d_out, int out_size, void* d_ws, size_t ws_size,
                              hipStream_t stream) {
  const float* x1 = (const float*)d_in[0];
  const float* x2 = (const float*)d_in[1];
  float* out = (float*)d_out;
  // grid: 1152 tiles x 3 dy-groups = 3456 blocks (divisible by 8 XCDs)
  corr_kernel<<<dim3(3456), dim3(BLOCK), 0, stream>>>(x1, x2, out);
}